// Round 12
// baseline (158.515 us; speedup 1.0000x reference)
//
#include <hip/hip_runtime.h>

#define B_SZ 32
#define L 4096
#define H 512
#define P 384
#define V 32
#define OUT_LEN 16
#define NSC 12        // super-chunks
#define SCLEN 340     // 4 interleaved streams x 85 steps
#define NSTEP 85
#define T0 4080       // NSC*SCLEN; 16-step tail = the 16 output states

// ---- ws layout (float offsets) ----
#define OFF_DBL   0         // [P][6] doubles (lbr,lbi,-,-,cr,ci)
#define OFF_LBF4  4608      // [P][2] float Lambda_bar^4
#define OFF_WPOW  5376      // [NSC][P][2] doubles: W^(NSC-1-c), W = Lbar^340
#define OFF_M     23808     // [V][P][2] UNSCALED dot table M0
#define OFF_CT    48384     // [P][2][H] transposed C
#define OFF_XACC  441600    // [B][P][2] float atomic accumulator for x(T0)
#define OFF_XS    466176    // [B][P][16][2] final states (coef applied)
#define OFF_YT    859392    // [512 r][512 h], r = b*16+l
#define OFF_HP    1121536   // [8][512][512] fc1 k-split partials
// end = 3218688 floats = 12.9 MB

// K1: bx<2: per-p double constants + wpow; bx in [2,194): C transpose;
//     bx<96: zero XACC; all 384 blocks: M0 (wave-unit = (p, 8-v group)).
__global__ __launch_bounds__(256) void k_prep(
    const float* __restrict__ embed,
    const float* __restrict__ Lre, const float* __restrict__ Lim,
    const float* __restrict__ Bre, const float* __restrict__ Bim,
    const float* __restrict__ Cre, const float* __restrict__ Cim,
    const float* __restrict__ log_step, float* __restrict__ ws)
{
    __shared__ float sre[32][33], sim[32][33];
    int bx = blockIdx.x, tid = threadIdx.x;
    if (bx < 96) ws[OFF_XACC + bx * 256 + tid] = 0.f;
    if (bx < 2) {
        int p = bx * 256 + tid;
        if (p < P) {
            double dstep = exp((double)log_step[p]);
            double are = (double)Lre[p] * dstep, aim = (double)Lim[p] * dstep;
            double mag = exp(are);
            double lbr = mag * cos(aim), lbi = mag * sin(aim);
            double lre = (double)Lre[p], lim = (double)Lim[p];
            double nr = lbr - 1.0, ni = lbi;
            double den = lre * lre + lim * lim;
            double cr = (nr * lre + ni * lim) / den, ci = (ni * lre - nr * lim) / den;
            double* d = (double*)ws + p * 6;
            d[0] = lbr; d[1] = lbi; d[2] = 0.0; d[3] = 0.0; d[4] = cr; d[5] = ci;
            double m4 = exp(4.0 * are), a4 = 4.0 * aim;
            ws[OFF_LBF4 + 2 * p]     = (float)(m4 * cos(a4));
            ws[OFF_LBF4 + 2 * p + 1] = (float)(m4 * sin(a4));
            double wmag = exp((double)SCLEN * are);
            double wang = (double)SCLEN * aim;
            double wr = wmag * cos(wang), wi = wmag * sin(wang);
            double* wpow = (double*)(ws + OFF_WPOW);
            double awr = 1.0, awi = 0.0;
            for (int c = NSC - 1; c >= 0; --c) {
                wpow[(c * P + p) * 2]     = awr;
                wpow[(c * P + p) * 2 + 1] = awi;
                double t = awr * wr - awi * wi;
                awi = awr * wi + awi * wr;
                awr = t;
            }
        }
    } else if (bx < 194) {
        int bxx = bx - 2;
        int tp = bxx >> 4, th = bxx & 15;
        int col = tid & 31, r0 = tid >> 5;
        #pragma unroll
        for (int it = 0; it < 4; ++it) {
            int row = r0 + 8 * it;
            int h = th * 32 + row, p = tp * 32 + col;
            sre[col][row] = Cre[h * P + p];
            sim[col][row] = Cim[h * P + p];
        }
        __syncthreads();
        #pragma unroll
        for (int it = 0; it < 4; ++it) {
            int pl = r0 + 8 * it;
            int p = tp * 32 + pl, h = th * 32 + col;
            ws[OFF_CT + (2 * p) * H + h]     = sre[pl][col];
            ws[OFF_CT + (2 * p + 1) * H + h] = sim[pl][col];
        }
    }
    {   // M0: 1536 wave-units over 384 blocks x 4 waves
        int w = bx * 4 + (tid >> 6);
        if (w < 1536) {
            int v0 = (w & 3) * 8, p = w >> 2;
            int lane = tid & 63;
            const float4* brp = (const float4*)(Bre + p * H);
            const float4* bip = (const float4*)(Bim + p * H);
            float4 br0 = brp[lane], br1 = brp[lane + 64];
            float4 bi0 = bip[lane], bi1 = bip[lane + 64];
            #pragma unroll
            for (int vv = 0; vv < 8; ++vv) {
                const float4* evp = (const float4*)(embed + (v0 + vv) * H);
                float4 e0 = evp[lane], e1 = evp[lane + 64];
                float dr = br0.x * e0.x;
                dr = fmaf(br0.y, e0.y, dr); dr = fmaf(br0.z, e0.z, dr);
                dr = fmaf(br0.w, e0.w, dr); dr = fmaf(br1.x, e1.x, dr);
                dr = fmaf(br1.y, e1.y, dr); dr = fmaf(br1.z, e1.z, dr);
                dr = fmaf(br1.w, e1.w, dr);
                float di = bi0.x * e0.x;
                di = fmaf(bi0.y, e0.y, di); di = fmaf(bi0.z, e0.z, di);
                di = fmaf(bi0.w, e0.w, di); di = fmaf(bi1.x, e1.x, di);
                di = fmaf(bi1.y, e1.y, di); di = fmaf(bi1.z, e1.z, di);
                di = fmaf(bi1.w, e1.w, di);
                #pragma unroll
                for (int off = 32; off; off >>= 1) {
                    dr += __shfl_down(dr, off);
                    di += __shfl_down(di, off);
                }
                if (lane == 0) {
                    ws[OFF_M + ((v0 + vv) * P + p) * 2]     = dr;
                    ws[OFF_M + ((v0 + vv) * P + p) * 2 + 1] = di;
                }
            }
        }
    }
}

// K2: super-chunk scan, 4 stride-interleaved streams, one int4 token load/iter.
__global__ __launch_bounds__(256) void k_scan(
    const int* __restrict__ tokens, float* __restrict__ ws)
{
    __shared__ float2 sM[V * 192];   // 48 KB -> 3 blocks/CU
    int x = blockIdx.x, b = blockIdx.y, tid = threadIdx.x;
    int ph = x & 1;
    int sc = x >> 1;
    const float2* Mg = (const float2*)(ws + OFF_M);
    for (int f = tid; f < V * 192; f += 256) {
        int v = f / 192, i = f - v * 192;
        sM[f] = Mg[v * P + ph * 192 + i];
    }
    __syncthreads();
    if (tid < 192) {
        int p = ph * 192 + tid;
        float Lr = ws[OFF_LBF4 + 2 * p], Li = ws[OFF_LBF4 + 2 * p + 1];
        const int4* tkb = (const int4*)(tokens + b * L + sc * SCLEN);
        float ar0 = 0, ai0 = 0, ar1 = 0, ai1 = 0;
        float ar2 = 0, ai2 = 0, ar3 = 0, ai3 = 0;
        int4 tq = tkb[0];
        #pragma unroll 5
        for (int i = 0; i < NSTEP; ++i) {
            int4 cur = tq;
            if (i + 1 < NSTEP) tq = tkb[i + 1];
            float2 m0 = sM[cur.x * 192 + tid];
            float2 m1 = sM[cur.y * 192 + tid];
            float2 m2 = sM[cur.z * 192 + tid];
            float2 m3 = sM[cur.w * 192 + tid];
            float n;
            n = fmaf(Lr, ar0, fmaf(-Li, ai0, m0.x));
            ai0 = fmaf(Lr, ai0, fmaf(Li, ar0, m0.y)); ar0 = n;
            n = fmaf(Lr, ar1, fmaf(-Li, ai1, m1.x));
            ai1 = fmaf(Lr, ai1, fmaf(Li, ar1, m1.y)); ar1 = n;
            n = fmaf(Lr, ar2, fmaf(-Li, ai2, m2.x));
            ai2 = fmaf(Lr, ai2, fmaf(Li, ar2, m2.y)); ar2 = n;
            n = fmaf(Lr, ar3, fmaf(-Li, ai3, m3.x));
            ai3 = fmaf(Lr, ai3, fmaf(Li, ar3, m3.y)); ar3 = n;
        }
        const double* d = (const double*)ws + p * 6;
        double l1r = d[0], l1i = d[1];
        double l2r = l1r * l1r - l1i * l1i, l2i = 2.0 * l1r * l1i;
        double l3r = l2r * l1r - l2i * l1i, l3i = l2r * l1i + l2i * l1r;
        double zr = l3r * ar0 - l3i * ai0 + l2r * ar1 - l2i * ai1
                  + l1r * ar2 - l1i * ai2 + (double)ar3;
        double zi = l3r * ai0 + l3i * ar0 + l2r * ai1 + l2i * ar1
                  + l1r * ai2 + l1i * ar2 + (double)ai3;
        const double* wpow = (const double*)(ws + OFF_WPOW);
        double wr = wpow[(sc * P + p) * 2], wi = wpow[(sc * P + p) * 2 + 1];
        float sr = (float)(wr * zr - wi * zi);
        float si = (float)(wr * zi + wi * zr);
        atomicAdd(ws + OFF_XACC + (b * P + p) * 2, sr);
        atomicAdd(ws + OFF_XACC + (b * P + p) * 2 + 1, si);
    }
}

// K3: 16-step tail ONCE per (b,p), coef applied, final float states -> XS.
// 192 blocks x 64 (one wave each, spread across CUs).
__global__ __launch_bounds__(64) void k_tail(
    const int* __restrict__ tokens, float* __restrict__ ws)
{
    int id = blockIdx.x * 64 + threadIdx.x;   // [0, 12288)
    int b = id / P, p = id - b * P;
    const double* d = (const double*)ws + p * 6;
    double lbr = d[0], lbi = d[1], cr = d[4], ci = d[5];
    const float2 za = *(const float2*)(ws + OFF_XACC + (b * P + p) * 2);
    double zr = (double)za.x, zi = (double)za.y;
    const float* M0 = ws + OFF_M;
    const int* tk = tokens + b * L + T0;
    float* xs = ws + OFF_XS + (b * P + p) * 32;
    #pragma unroll
    for (int j = 0; j < OUT_LEN; ++j) {
        int t = tk[j];
        double mr = (double)M0[(t * P + p) * 2];
        double mi = (double)M0[(t * P + p) * 2 + 1];
        double tr = lbr * zr - lbi * zi + mr;
        double ti = lbr * zi + lbi * zr + mi;
        zr = tr; zi = ti;
        xs[2 * j]     = (float)(cr * zr - ci * zi);
        xs[2 * j + 1] = (float)(cr * zi + ci * zr);
    }
}

// K4: y -> Yt. 512 blocks = b(32) x (hq*2+lh)(16), 256 thr = (hl 64, pg 4).
// x states read via uniform-address global loads (scalar-cache path);
// LDS used only for the 9 KB partial-reduce buffer.
__global__ __launch_bounds__(256) void k_y(
    const int* __restrict__ tokens, const float* __restrict__ embed,
    const float* __restrict__ D, const float* __restrict__ xs,
    const float* __restrict__ ct, float* __restrict__ yt)
{
    __shared__ float sred[4 * 64 * 9];   // 9 KB
    int bx = blockIdx.x, tid = threadIdx.x;
    int b = bx >> 4, x = bx & 15;
    int lh = x & 1, hq = x >> 1;
    int hl = tid & 63, pg = tid >> 6;
    int h = hq * 64 + hl;
    const float* xb = xs + b * (P * 32) + lh * 16;   // uniform per (block,p)
    float acc[8];
    #pragma unroll
    for (int i = 0; i < 8; ++i) acc[i] = 0.f;
    int p0 = pg * 96;
    float pr_[4], pi_[4];
    #pragma unroll
    for (int u = 0; u < 4; ++u) {
        pr_[u] = ct[(2 * (p0 + u)) * H + h];
        pi_[u] = ct[(2 * (p0 + u) + 1) * H + h];
    }
    for (int qs = 0; qs < 96; qs += 4) {
        float cr_[4], ci_[4];
        #pragma unroll
        for (int u = 0; u < 4; ++u) { cr_[u] = pr_[u]; ci_[u] = pi_[u]; }
        if (qs + 4 < 96) {
            #pragma unroll
            for (int u = 0; u < 4; ++u) {
                pr_[u] = ct[(2 * (p0 + qs + 4 + u)) * H + h];
                pi_[u] = ct[(2 * (p0 + qs + 4 + u) + 1) * H + h];
            }
        }
        #pragma unroll
        for (int u = 0; u < 4; ++u) {
            const float4* xv = (const float4*)(xb + (p0 + qs + u) * 32);
            float4 x0 = xv[0], x1 = xv[1], x2 = xv[2], x3 = xv[3];
            float cre = cr_[u], cim = ci_[u];
            acc[0] = fmaf(cre, x0.x, fmaf(-cim, x0.y, acc[0]));
            acc[1] = fmaf(cre, x0.z, fmaf(-cim, x0.w, acc[1]));
            acc[2] = fmaf(cre, x1.x, fmaf(-cim, x1.y, acc[2]));
            acc[3] = fmaf(cre, x1.z, fmaf(-cim, x1.w, acc[3]));
            acc[4] = fmaf(cre, x2.x, fmaf(-cim, x2.y, acc[4]));
            acc[5] = fmaf(cre, x2.z, fmaf(-cim, x2.w, acc[5]));
            acc[6] = fmaf(cre, x3.x, fmaf(-cim, x3.y, acc[6]));
            acc[7] = fmaf(cre, x3.z, fmaf(-cim, x3.w, acc[7]));
        }
    }
    #pragma unroll
    for (int i = 0; i < 8; ++i)
        sred[(pg * 64 + hl) * 9 + i] = acc[i];
    __syncthreads();
    #pragma unroll
    for (int oo = 0; oo < 2; ++oo) {
        int o = tid + 256 * oo;
        int ohl = o & 63, oi = o >> 6;
        float s = sred[ohl * 9 + oi] + sred[(64 + ohl) * 9 + oi]
                + sred[(128 + ohl) * 9 + oi] + sred[(192 + ohl) * 9 + oi];
        int l = lh * 8 + oi;
        int t = tokens[b * L + T0 + l];
        int hh = hq * 64 + ohl;
        yt[(b * OUT_LEN + l) * H + hh] =
            2.f * s + embed[t * H + hh] * D[hh];
    }
}

// K5: GEMM1 partials, 8-way k-split (K=64), 16 rows/block, depth-8 prefetch.
__global__ __launch_bounds__(256) void k_fc1(
    const float* __restrict__ W1, const float* __restrict__ ws,
    float* __restrict__ hp)
{
    __shared__ __align__(16) float ys[64 * 16];   // 4 KB
    int bx = blockIdx.x, tid = threadIdx.x;
    int rg = bx >> 4, jh = (bx >> 3) & 1, kc = bx & 7;
    int j = jh * 256 + tid;
    int r0 = rg * 16, k0 = kc * 64;
    const float* yt = ws + OFF_YT;
    int row = tid & 15, kk4 = tid >> 4;
    #pragma unroll
    for (int it = 0; it < 4; ++it) {
        int k = kk4 + 16 * it;
        ys[k * 16 + row] = yt[(r0 + row) * H + k0 + k];
    }
    __syncthreads();
    const float* wp = W1 + k0 * H + j;
    float wreg[8];
    #pragma unroll
    for (int u = 0; u < 8; ++u) wreg[u] = wp[u * H];
    float acc[16];
    #pragma unroll
    for (int i = 0; i < 16; ++i) acc[i] = 0.f;
    for (int kb = 0; kb < 64; kb += 8) {
        float cur[8];
        #pragma unroll
        for (int u = 0; u < 8; ++u) cur[u] = wreg[u];
        if (kb + 8 < 64) {
            #pragma unroll
            for (int u = 0; u < 8; ++u) wreg[u] = wp[(kb + 8 + u) * H];
        }
        #pragma unroll
        for (int u = 0; u < 8; ++u) {
            const float4* y0 = (const float4*)(ys + (kb + u) * 16);
            float4 p0 = y0[0], p1 = y0[1], p2 = y0[2], p3 = y0[3];
            float a = cur[u];
            acc[0]  = fmaf(p0.x, a, acc[0]);
            acc[1]  = fmaf(p0.y, a, acc[1]);
            acc[2]  = fmaf(p0.z, a, acc[2]);
            acc[3]  = fmaf(p0.w, a, acc[3]);
            acc[4]  = fmaf(p1.x, a, acc[4]);
            acc[5]  = fmaf(p1.y, a, acc[5]);
            acc[6]  = fmaf(p1.z, a, acc[6]);
            acc[7]  = fmaf(p1.w, a, acc[7]);
            acc[8]  = fmaf(p2.x, a, acc[8]);
            acc[9]  = fmaf(p2.y, a, acc[9]);
            acc[10] = fmaf(p2.z, a, acc[10]);
            acc[11] = fmaf(p2.w, a, acc[11]);
            acc[12] = fmaf(p3.x, a, acc[12]);
            acc[13] = fmaf(p3.y, a, acc[13]);
            acc[14] = fmaf(p3.z, a, acc[14]);
            acc[15] = fmaf(p3.w, a, acc[15]);
        }
    }
    #pragma unroll
    for (int i = 0; i < 16; ++i)
        hp[(kc * 512 + r0 + i) * H + j] = acc[i];
}

// K6: per-row reduce of 8 partials + relu + GEMM2. 512 blocks x 256.
__global__ __launch_bounds__(256) void k_fc2(
    const float* __restrict__ b1, const float* __restrict__ W2,
    const float* __restrict__ b2, const float* __restrict__ hp,
    float* __restrict__ out)
{
    __shared__ float sh[512];
    __shared__ float red[8 * 32];
    int r = blockIdx.x, tid = threadIdx.x;
    #pragma unroll
    for (int half = 0; half < 2; ++half) {
        int j = half * 256 + tid;
        float s = b1[j];
        #pragma unroll
        for (int m = 0; m < 8; ++m)
            s += hp[(m * 512 + r) * H + j];
        sh[j] = fmaxf(s, 0.f);
    }
    __syncthreads();
    int seg = tid >> 5, o = tid & 31;
    const float* w2 = W2 + seg * 64 * V + o;
    const float* hv = sh + seg * 64;
    float a0 = 0.f, a1 = 0.f, a2 = 0.f, a3 = 0.f;
    #pragma unroll
    for (int q = 0; q < 16; ++q) {
        a0 = fmaf(hv[q],      w2[q * V],        a0);
        a1 = fmaf(hv[16 + q], w2[(16 + q) * V], a1);
        a2 = fmaf(hv[32 + q], w2[(32 + q) * V], a2);
        a3 = fmaf(hv[48 + q], w2[(48 + q) * V], a3);
    }
    red[seg * 32 + o] = (a0 + a1) + (a2 + a3);
    __syncthreads();
    if (tid < 32) {
        float s = b2[tid];
        #pragma unroll
        for (int ss = 0; ss < 8; ++ss) s += red[ss * 32 + tid];
        out[r * V + tid] = s;
    }
}

extern "C" void kernel_launch(void* const* d_in, const int* in_sizes, int n_in,
                              void* d_out, int out_size, void* d_ws, size_t ws_size,
                              hipStream_t stream)
{
    const int*   tokens = (const int*)d_in[0];
    const float* embed  = (const float*)d_in[1];
    const float* Lre    = (const float*)d_in[2];
    const float* Lim    = (const float*)d_in[3];
    const float* Bre    = (const float*)d_in[4];
    const float* Bim    = (const float*)d_in[5];
    const float* Cre    = (const float*)d_in[6];
    const float* Cim    = (const float*)d_in[7];
    const float* D      = (const float*)d_in[8];
    const float* lstep  = (const float*)d_in[9];
    const float* W1     = (const float*)d_in[10];
    const float* b1     = (const float*)d_in[11];
    const float* W2     = (const float*)d_in[12];
    const float* b2     = (const float*)d_in[13];
    float* out = (float*)d_out;
    float* ws  = (float*)d_ws;

    k_prep<<<384, 256, 0, stream>>>(embed, Lre, Lim, Bre, Bim,
                                    Cre, Cim, lstep, ws);
    k_scan<<<dim3(24, 32), 256, 0, stream>>>(tokens, ws);
    k_tail<<<192, 64, 0, stream>>>(tokens, ws);
    k_y   <<<512, 256, 0, stream>>>(tokens, embed, D,
                                    ws + OFF_XS, ws + OFF_CT, ws + OFF_YT);
    k_fc1 <<<512, 256, 0, stream>>>(W1, ws, ws + OFF_HP);
    k_fc2 <<<512, 256, 0, stream>>>(b1, W2, b2, ws + OFF_HP, out);
}

// Round 13
// 140.446 us; speedup vs baseline: 1.1287x; 1.1287x over previous
//
#include <hip/hip_runtime.h>

#define B_SZ 32
#define L 4096
#define H 512
#define P 384
#define V 32
#define OUT_LEN 16
#define NSC 12        // super-chunks
#define SCLEN 340     // 4 interleaved streams x 85 steps
#define NSTEP 85
#define T0 4080       // NSC*SCLEN; 16-step tail = the 16 output states

// ---- ws layout (float offsets) ----
#define OFF_DBL   0         // [P][6] doubles (lbr,lbi,-,-,cr,ci)
#define OFF_LBF4  4608      // [P][2] float Lambda_bar^4
#define OFF_WPOW  5376      // [NSC][P][2] doubles: W^(NSC-1-c), W = Lbar^340
#define OFF_M     23808     // [V][P][2] UNSCALED dot table M0
#define OFF_CT    48384     // [P][2][H] transposed C
#define OFF_XACC  441600    // [B][P][2] float atomic accumulator for x(T0)
#define OFF_YT    466176    // [512 r][512 h], r = b*16+l
#define OFF_HP    728320    // [4][512][512] fc1 k-split partials
// end = 1776896 floats = 7.1 MB

// K1: bx<2: per-p double constants + wpow; bx in [2,194): C transpose;
//     bx<96: zero XACC; all 384 blocks: M0 (wave-unit = (p, 8-v group)).
__global__ __launch_bounds__(256) void k_prep(
    const float* __restrict__ embed,
    const float* __restrict__ Lre, const float* __restrict__ Lim,
    const float* __restrict__ Bre, const float* __restrict__ Bim,
    const float* __restrict__ Cre, const float* __restrict__ Cim,
    const float* __restrict__ log_step, float* __restrict__ ws)
{
    __shared__ float sre[32][33], sim[32][33];
    int bx = blockIdx.x, tid = threadIdx.x;
    if (bx < 96) ws[OFF_XACC + bx * 256 + tid] = 0.f;   // zero XACC (24576 floats)
    if (bx < 2) {
        int p = bx * 256 + tid;
        if (p < P) {
            double dstep = exp((double)log_step[p]);
            double are = (double)Lre[p] * dstep, aim = (double)Lim[p] * dstep;
            double mag = exp(are);
            double lbr = mag * cos(aim), lbi = mag * sin(aim);
            double lre = (double)Lre[p], lim = (double)Lim[p];
            double nr = lbr - 1.0, ni = lbi;
            double den = lre * lre + lim * lim;
            double cr = (nr * lre + ni * lim) / den, ci = (ni * lre - nr * lim) / den;
            double* d = (double*)ws + p * 6;
            d[0] = lbr; d[1] = lbi; d[2] = 0.0; d[3] = 0.0; d[4] = cr; d[5] = ci;
            // Lbar^4 (float, for the interleaved streams)
            double m4 = exp(4.0 * are), a4 = 4.0 * aim;
            ws[OFF_LBF4 + 2 * p]     = (float)(m4 * cos(a4));
            ws[OFF_LBF4 + 2 * p + 1] = (float)(m4 * sin(a4));
            // W = Lbar^340; wpow[c] = W^(NSC-1-c)
            double wmag = exp((double)SCLEN * are);
            double wang = (double)SCLEN * aim;
            double wr = wmag * cos(wang), wi = wmag * sin(wang);
            double* wpow = (double*)(ws + OFF_WPOW);
            double awr = 1.0, awi = 0.0;
            for (int c = NSC - 1; c >= 0; --c) {
                wpow[(c * P + p) * 2]     = awr;
                wpow[(c * P + p) * 2 + 1] = awi;
                double t = awr * wr - awi * wi;
                awi = awr * wi + awi * wr;
                awr = t;
            }
        }
    } else if (bx < 194) {
        int bxx = bx - 2;
        int tp = bxx >> 4, th = bxx & 15;        // 12 p-tiles x 16 h-tiles
        int col = tid & 31, r0 = tid >> 5;
        #pragma unroll
        for (int it = 0; it < 4; ++it) {
            int row = r0 + 8 * it;
            int h = th * 32 + row, p = tp * 32 + col;
            sre[col][row] = Cre[h * P + p];
            sim[col][row] = Cim[h * P + p];
        }
        __syncthreads();
        #pragma unroll
        for (int it = 0; it < 4; ++it) {
            int pl = r0 + 8 * it;
            int p = tp * 32 + pl, h = th * 32 + col;
            ws[OFF_CT + (2 * p) * H + h]     = sre[pl][col];
            ws[OFF_CT + (2 * p + 1) * H + h] = sim[pl][col];
        }
    }
    {   // M0: 1536 wave-units over 384 blocks x 4 waves
        int w = bx * 4 + (tid >> 6);
        if (w < 1536) {
            int v0 = (w & 3) * 8, p = w >> 2;
            int lane = tid & 63;
            const float4* brp = (const float4*)(Bre + p * H);
            const float4* bip = (const float4*)(Bim + p * H);
            float4 br0 = brp[lane], br1 = brp[lane + 64];
            float4 bi0 = bip[lane], bi1 = bip[lane + 64];
            #pragma unroll
            for (int vv = 0; vv < 8; ++vv) {
                const float4* evp = (const float4*)(embed + (v0 + vv) * H);
                float4 e0 = evp[lane], e1 = evp[lane + 64];
                float dr = br0.x * e0.x;
                dr = fmaf(br0.y, e0.y, dr); dr = fmaf(br0.z, e0.z, dr);
                dr = fmaf(br0.w, e0.w, dr); dr = fmaf(br1.x, e1.x, dr);
                dr = fmaf(br1.y, e1.y, dr); dr = fmaf(br1.z, e1.z, dr);
                dr = fmaf(br1.w, e1.w, dr);
                float di = bi0.x * e0.x;
                di = fmaf(bi0.y, e0.y, di); di = fmaf(bi0.z, e0.z, di);
                di = fmaf(bi0.w, e0.w, di); di = fmaf(bi1.x, e1.x, di);
                di = fmaf(bi1.y, e1.y, di); di = fmaf(bi1.z, e1.z, di);
                di = fmaf(bi1.w, e1.w, di);
                #pragma unroll
                for (int off = 32; off; off >>= 1) {
                    dr += __shfl_down(dr, off);
                    di += __shfl_down(di, off);
                }
                if (lane == 0) {
                    ws[OFF_M + ((v0 + vv) * P + p) * 2]     = dr;
                    ws[OFF_M + ((v0 + vv) * P + p) * 2 + 1] = di;
                }
            }
        }
    }
}

// K2: super-chunk scan, 4 stride-interleaved streams, one int4 token load/iter.
// grid (24, 32): x = ph + 2*sc, y = b. Stream s covers positions 4i+s.
// partial = sum_s Lbar^(3-s)*S_s ; scaled by wpow[sc] ; atomicAdd into XACC.
__global__ __launch_bounds__(256) void k_scan(
    const int* __restrict__ tokens, float* __restrict__ ws)
{
    __shared__ float2 sM[V * 192];   // 48 KB -> 3 blocks/CU
    int x = blockIdx.x, b = blockIdx.y, tid = threadIdx.x;
    int ph = x & 1;
    int sc = x >> 1;                          // [0,12)
    const float2* Mg = (const float2*)(ws + OFF_M);
    for (int f = tid; f < V * 192; f += 256) {
        int v = f / 192, i = f - v * 192;
        sM[f] = Mg[v * P + ph * 192 + i];
    }
    __syncthreads();
    if (tid < 192) {
        int p = ph * 192 + tid;
        float Lr = ws[OFF_LBF4 + 2 * p], Li = ws[OFF_LBF4 + 2 * p + 1];
        const int4* tkb = (const int4*)(tokens + b * L + sc * SCLEN);  // 16B-aligned
        float ar0 = 0, ai0 = 0, ar1 = 0, ai1 = 0;
        float ar2 = 0, ai2 = 0, ar3 = 0, ai3 = 0;
        int4 tq = tkb[0];
        #pragma unroll 5
        for (int i = 0; i < NSTEP; ++i) {
            int4 cur = tq;
            if (i + 1 < NSTEP) tq = tkb[i + 1];   // uniform prefetch (next stage)
            float2 m0 = sM[cur.x * 192 + tid];
            float2 m1 = sM[cur.y * 192 + tid];
            float2 m2 = sM[cur.z * 192 + tid];
            float2 m3 = sM[cur.w * 192 + tid];
            float n;
            n = fmaf(Lr, ar0, fmaf(-Li, ai0, m0.x));
            ai0 = fmaf(Lr, ai0, fmaf(Li, ar0, m0.y)); ar0 = n;
            n = fmaf(Lr, ar1, fmaf(-Li, ai1, m1.x));
            ai1 = fmaf(Lr, ai1, fmaf(Li, ar1, m1.y)); ar1 = n;
            n = fmaf(Lr, ar2, fmaf(-Li, ai2, m2.x));
            ai2 = fmaf(Lr, ai2, fmaf(Li, ar2, m2.y)); ar2 = n;
            n = fmaf(Lr, ar3, fmaf(-Li, ai3, m3.x));
            ai3 = fmaf(Lr, ai3, fmaf(Li, ar3, m3.y)); ar3 = n;
        }
        // combine streams: z = L^3*S0 + L^2*S1 + L*S2 + S3  (double)
        const double* d = (const double*)ws + p * 6;
        double l1r = d[0], l1i = d[1];
        double l2r = l1r * l1r - l1i * l1i, l2i = 2.0 * l1r * l1i;
        double l3r = l2r * l1r - l2i * l1i, l3i = l2r * l1i + l2i * l1r;
        double zr = l3r * ar0 - l3i * ai0 + l2r * ar1 - l2i * ai1
                  + l1r * ar2 - l1i * ai2 + (double)ar3;
        double zi = l3r * ai0 + l3i * ar0 + l2r * ai1 + l2i * ar1
                  + l1r * ai2 + l1i * ar2 + (double)ai3;
        // scale by wpow[sc] and accumulate
        const double* wpow = (const double*)(ws + OFF_WPOW);
        double wr = wpow[(sc * P + p) * 2], wi = wpow[(sc * P + p) * 2 + 1];
        float sr = (float)(wr * zr - wi * zi);
        float si = (float)(wr * zi + wi * zr);
        atomicAdd(ws + OFF_XACC + (b * P + p) * 2, sr);
        atomicAdd(ws + OFF_XACC + (b * P + p) * 2 + 1, si);
    }
}

// K3: read x(T0) + 16-step tail (double) + y -> Yt. 512 blocks = b(32) x (hq*2+lh)(16).
__global__ __launch_bounds__(256) void k_y(
    const int* __restrict__ tokens, const float* __restrict__ embed,
    const float* __restrict__ D, float* __restrict__ ws)
{
    __shared__ float sxs[P * 16];        // 24 KB
    __shared__ float sred[4 * 64 * 9];   // 9 KB
    int bx = blockIdx.x, tid = threadIdx.x;
    int b = bx >> 4, x = bx & 15;
    int lh = x & 1, hq = x >> 1;
    // phase A: tail recurrence from accumulated x(T0)
    #pragma unroll
    for (int pass = 0; pass < 2; ++pass) {
        int p = tid + pass * 256;
        if (p < P) {
            const double* d = (const double*)ws + p * 6;
            double lbr = d[0], lbi = d[1], cr = d[4], ci = d[5];
            const float2 za = *(const float2*)(ws + OFF_XACC + (b * P + p) * 2);
            double zr = (double)za.x, zi = (double)za.y;
            const float* M0 = ws + OFF_M;
            const int* tk = tokens + b * L + T0;
            #pragma unroll
            for (int j = 0; j < OUT_LEN; ++j) {
                int t = tk[j];
                double mr = (double)M0[(t * P + p) * 2];
                double mi = (double)M0[(t * P + p) * 2 + 1];
                double tr = lbr * zr - lbi * zi + mr;
                double ti = lbr * zi + lbi * zr + mi;
                zr = tr; zi = ti;
                if ((j >> 3) == lh) {
                    int jl = j & 7;
                    sxs[p * 16 + 2 * jl]     = (float)(cr * zr - ci * zi);
                    sxs[p * 16 + 2 * jl + 1] = (float)(cr * zi + ci * zr);
                }
            }
        }
    }
    __syncthreads();
    // phase B: 8 l-accs over 96 p; depth-4 CT prefetch; LDS broadcast x
    int hl = tid & 63, pg = tid >> 6;
    int h = hq * 64 + hl;
    const float* ct = ws + OFF_CT;
    float acc[8];
    #pragma unroll
    for (int i = 0; i < 8; ++i) acc[i] = 0.f;
    int p0 = pg * 96;
    float pr_[4], pi_[4];
    #pragma unroll
    for (int u = 0; u < 4; ++u) {
        pr_[u] = ct[(2 * (p0 + u)) * H + h];
        pi_[u] = ct[(2 * (p0 + u) + 1) * H + h];
    }
    for (int qs = 0; qs < 96; qs += 4) {
        float cr_[4], ci_[4];
        #pragma unroll
        for (int u = 0; u < 4; ++u) { cr_[u] = pr_[u]; ci_[u] = pi_[u]; }
        if (qs + 4 < 96) {
            #pragma unroll
            for (int u = 0; u < 4; ++u) {
                pr_[u] = ct[(2 * (p0 + qs + 4 + u)) * H + h];
                pi_[u] = ct[(2 * (p0 + qs + 4 + u) + 1) * H + h];
            }
        }
        #pragma unroll
        for (int u = 0; u < 4; ++u) {
            const float4* xv = (const float4*)(sxs + (p0 + qs + u) * 16);
            float4 x0 = xv[0], x1 = xv[1], x2 = xv[2], x3 = xv[3];
            float cre = cr_[u], cim = ci_[u];
            acc[0] = fmaf(cre, x0.x, fmaf(-cim, x0.y, acc[0]));
            acc[1] = fmaf(cre, x0.z, fmaf(-cim, x0.w, acc[1]));
            acc[2] = fmaf(cre, x1.x, fmaf(-cim, x1.y, acc[2]));
            acc[3] = fmaf(cre, x1.z, fmaf(-cim, x1.w, acc[3]));
            acc[4] = fmaf(cre, x2.x, fmaf(-cim, x2.y, acc[4]));
            acc[5] = fmaf(cre, x2.z, fmaf(-cim, x2.w, acc[5]));
            acc[6] = fmaf(cre, x3.x, fmaf(-cim, x3.y, acc[6]));
            acc[7] = fmaf(cre, x3.z, fmaf(-cim, x3.w, acc[7]));
        }
    }
    #pragma unroll
    for (int i = 0; i < 8; ++i)
        sred[(pg * 64 + hl) * 9 + i] = acc[i];
    __syncthreads();
    // phase C
    #pragma unroll
    for (int oo = 0; oo < 2; ++oo) {
        int o = tid + 256 * oo;
        int ohl = o & 63, oi = o >> 6;
        float s = sred[ohl * 9 + oi] + sred[(64 + ohl) * 9 + oi]
                + sred[(128 + ohl) * 9 + oi] + sred[(192 + ohl) * 9 + oi];
        int l = lh * 8 + oi;
        int t = tokens[b * L + T0 + l];
        int hh = hq * 64 + ohl;
        ws[OFF_YT + (b * OUT_LEN + l) * H + hh] =
            2.f * s + embed[t * H + hh] * D[hh];
    }
}

// K4: GEMM1 partials, 4-way k-split, depth-8 prefetch, packed ys[k][8r].
__global__ __launch_bounds__(256) void k_fc1(
    const float* __restrict__ W1, const float* __restrict__ ws,
    float* __restrict__ hp)
{
    __shared__ float ys[128 * 8];
    int bx = blockIdx.x, tid = threadIdx.x;
    int rg = bx >> 3, jh = (bx >> 2) & 1, kc = bx & 3;
    int j = jh * 256 + tid;
    int r0 = rg * 8, k0 = kc * 128;
    const float* yt = ws + OFF_YT;
    int kk = tid & 127, rr = tid >> 7;
    #pragma unroll
    for (int it = 0; it < 4; ++it)
        ys[kk * 8 + rr + 2 * it] = yt[(r0 + rr + 2 * it) * H + k0 + kk];
    __syncthreads();
    const float* wp = W1 + k0 * H + j;
    float wreg[8];
    #pragma unroll
    for (int u = 0; u < 8; ++u) wreg[u] = wp[u * H];
    float acc[8] = {0, 0, 0, 0, 0, 0, 0, 0};
    for (int kb = 0; kb < 128; kb += 8) {
        float cur[8];
        #pragma unroll
        for (int u = 0; u < 8; ++u) cur[u] = wreg[u];
        if (kb + 8 < 128) {
            #pragma unroll
            for (int u = 0; u < 8; ++u) wreg[u] = wp[(kb + 8 + u) * H];
        }
        #pragma unroll
        for (int u = 0; u < 8; ++u) {
            const float4* y0 = (const float4*)(ys + (kb + u) * 8);
            float4 p0 = y0[0], p1 = y0[1];
            float a = cur[u];
            acc[0] = fmaf(p0.x, a, acc[0]);
            acc[1] = fmaf(p0.y, a, acc[1]);
            acc[2] = fmaf(p0.z, a, acc[2]);
            acc[3] = fmaf(p0.w, a, acc[3]);
            acc[4] = fmaf(p1.x, a, acc[4]);
            acc[5] = fmaf(p1.y, a, acc[5]);
            acc[6] = fmaf(p1.z, a, acc[6]);
            acc[7] = fmaf(p1.w, a, acc[7]);
        }
    }
    #pragma unroll
    for (int i = 0; i < 8; ++i)
        hp[(kc * 512 + r0 + i) * H + j] = acc[i];
}

// K5: per-row reduce + relu + GEMM2. 512 blocks x 256. 4-acc unroll.
__global__ __launch_bounds__(256) void k_fc2(
    const float* __restrict__ b1, const float* __restrict__ W2,
    const float* __restrict__ b2, const float* __restrict__ hp,
    float* __restrict__ out)
{
    __shared__ float sh[512];
    __shared__ float red[8 * 32];
    int r = blockIdx.x, tid = threadIdx.x;
    #pragma unroll
    for (int half = 0; half < 2; ++half) {
        int j = half * 256 + tid;
        float s = b1[j] + hp[r * H + j] + hp[(512 + r) * H + j]
                        + hp[(1024 + r) * H + j] + hp[(1536 + r) * H + j];
        sh[j] = fmaxf(s, 0.f);
    }
    __syncthreads();
    int seg = tid >> 5, o = tid & 31;
    const float* w2 = W2 + seg * 64 * V + o;
    const float* hv = sh + seg * 64;
    float a0 = 0.f, a1 = 0.f, a2 = 0.f, a3 = 0.f;
    #pragma unroll
    for (int q = 0; q < 16; ++q) {
        a0 = fmaf(hv[q],      w2[q * V],        a0);
        a1 = fmaf(hv[16 + q], w2[(16 + q) * V], a1);
        a2 = fmaf(hv[32 + q], w2[(32 + q) * V], a2);
        a3 = fmaf(hv[48 + q], w2[(48 + q) * V], a3);
    }
    red[seg * 32 + o] = (a0 + a1) + (a2 + a3);
    __syncthreads();
    if (tid < 32) {
        float s = b2[tid];
        #pragma unroll
        for (int ss = 0; ss < 8; ++ss) s += red[ss * 32 + tid];
        out[r * V + tid] = s;
    }
}

extern "C" void kernel_launch(void* const* d_in, const int* in_sizes, int n_in,
                              void* d_out, int out_size, void* d_ws, size_t ws_size,
                              hipStream_t stream)
{
    const int*   tokens = (const int*)d_in[0];
    const float* embed  = (const float*)d_in[1];
    const float* Lre    = (const float*)d_in[2];
    const float* Lim    = (const float*)d_in[3];
    const float* Bre    = (const float*)d_in[4];
    const float* Bim    = (const float*)d_in[5];
    const float* Cre    = (const float*)d_in[6];
    const float* Cim    = (const float*)d_in[7];
    const float* D      = (const float*)d_in[8];
    const float* lstep  = (const float*)d_in[9];
    const float* W1     = (const float*)d_in[10];
    const float* b1     = (const float*)d_in[11];
    const float* W2     = (const float*)d_in[12];
    const float* b2     = (const float*)d_in[13];
    float* out = (float*)d_out;
    float* ws  = (float*)d_ws;

    k_prep<<<384, 256, 0, stream>>>(embed, Lre, Lim, Bre, Bim,
                                    Cre, Cim, lstep, ws);
    k_scan<<<dim3(24, 32), 256, 0, stream>>>(tokens, ws);
    k_y   <<<512, 256, 0, stream>>>(tokens, embed, D, ws);
    k_fc1 <<<512, 256, 0, stream>>>(W1, ws, ws + OFF_HP);
    k_fc2 <<<512, 256, 0, stream>>>(b1, W2, b2, ws + OFF_HP, out);
}